// Round 14
// baseline (2827.259 us; speedup 1.0000x reference)
//
#include <hip/hip_runtime.h>
#include <stdint.h>

// Teacher-forced LSTM, B=64 T=512 D=H=1024.
// gates(t) = m(t)*(h@Wx^T) + (1-m(t))*(x(t)@Wx^T) + h@Wh^T + bias, h=h(t-1)
// x(t+1)@Wx^T is computed in step t's barrier SLACK (after own flag store,
// before gen poll) from pre-packed bf16 xp with plain cached loads.
// Persistent: 256 blocks x 512 thr = 128 unit-groups x 2 batch-halves.
// Block (ug,bg): 32 batches x 8 units (32 gate rows). h-only panel:
// hbuf[2][128 kblk][64 b][8] bf16 -> 64KB read per block per step.
// Weights bf16 128KB LDS-stationary, conflict-free. 32x32x16 MFMA;
// 8 waves = 8 K-eighths of 1024; 4-slab 2-phase reduce.
// Producers: agent write-through h stores. Consumers: agent atomic 8B loads.
// Barrier: R11-VERBATIM master/gen (R12 lesson: master hop is load-bearing).
// R14 fix vs R13: epilogue blend mask index is ml[b0+br], not ml[br]
// (bg=1 blocks were using the wrong batch half's masks).

#define B_ 64
#define T_ 512
#define D_ 1024
#define H_ 1024
#define NBLK 256
#define UPB 8
#define NROW 32
#define NTHR 512

typedef __attribute__((ext_vector_type(8))) short short8;
typedef __attribute__((ext_vector_type(16))) float f32x16;

// LDS (bytes): Wx @0 64KB | Wh @65536 64KB | gbuf f32[4][32][33] @131072 |
// m_lds f32[2][64] @147968 | bias f32[32] @148480
#define WH_OFF 65536
#define GBUF_OFF 131072
#define MLDS_OFF 147968
#define BIAS_OFF 148480
#define SMEM_BYTES 148608

// ws (bytes): flags[256] u32 @0 | gen u32 @2048 | mT f32[512][64] @4096 |
// hbuf @135168: [2][128 kblk][64 b][8] bf16 | xp @397312: [512 t][128][64][8] bf16
#define WS_MT 4096
#define WS_HBUF 135168
#define WS_XP 397312
#define HSLOT 65536 /* shorts per h slot (131072 B) */

__device__ __forceinline__ unsigned f2bf(float f) {  // fp32 -> bf16 RNE
  unsigned u = __float_as_uint(f);
  return (u + 0x7FFFu + ((u >> 16) & 1u)) >> 16;
}
__device__ __forceinline__ float sigf(float x) { return 1.0f / (1.0f + __expf(-x)); }
__device__ __forceinline__ float tanhf_(float x) { return 1.0f - 2.0f / (__expf(2.0f * x) + 1.0f); }

__global__ void prep_m(const float* __restrict__ tm, float* __restrict__ mT) {
  int i = blockIdx.x * blockDim.x + threadIdx.x;  // over B*T
  if (i >= B_ * T_) return;
  int b = i >> 9, t = i & (T_ - 1);
  mT[t * B_ + b] = tm[i];
}

// xp[((t*128 + dblk)*64 + b)*8 + s] = bf16(x[b][t][dblk*8+s]); coalesced reads.
__global__ void prep_x(const float* __restrict__ x, unsigned short* __restrict__ xp) {
  int i = blockIdx.x * blockDim.x + threadIdx.x;  // over B*T*D/8
  if (i >= B_ * T_ * D_ / 8) return;
  const int dblk = i & 127, t = (i >> 7) & (T_ - 1), b = i >> 16;
  const float* src = x + ((size_t)b * T_ + t) * D_ + dblk * 8;
  float4 a0 = *(const float4*)src;
  float4 a1 = *(const float4*)(src + 4);
  short8 r;
  r[0] = (short)f2bf(a0.x); r[1] = (short)f2bf(a0.y);
  r[2] = (short)f2bf(a0.z); r[3] = (short)f2bf(a0.w);
  r[4] = (short)f2bf(a1.x); r[5] = (short)f2bf(a1.y);
  r[6] = (short)f2bf(a1.z); r[7] = (short)f2bf(a1.w);
  *(short8*)(xp + ((size_t)(t * 128 + dblk) * 64 + b) * 8) = r;
}

template<int XB>
__global__ __launch_bounds__(NTHR, 1)
void lstm_persist(const float* __restrict__ xf,
                  const unsigned short* __restrict__ xp,
                  const float* __restrict__ mT,
                  const float* __restrict__ Wx, const float* __restrict__ bxp,
                  const float* __restrict__ Wh, const float* __restrict__ bhp,
                  float* __restrict__ out,
                  unsigned short* __restrict__ hbuf,
                  unsigned* __restrict__ flags,
                  unsigned* __restrict__ gen)
{
  extern __shared__ char smem[];
  float* gbuf     = (float*)(smem + GBUF_OFF);  // [4][32][33]
  float* m_lds    = (float*)(smem + MLDS_OFF);  // [2][64]
  float* bias_lds = (float*)(smem + BIAS_OFF);

  const int tid = threadIdx.x;
  const int bid = blockIdx.x;
  const int ug  = bid >> 1;   // unit group 0..127
  const int bg  = bid & 1;    // batch half

  // ---- stage Wx,Wh -> LDS, conflict-free layout ----
  // dword s (0..16383): dw=s&3, n=(s>>2)&31, kg=(s>>7)&1, j=(s>>8)&7, ko=s>>11
  // byte = ko*8192 + j*1024 + kg*512 + n*16 + dw*4 ; k = ko*128+j*16+kg*8+dw*2
  for (int i = 0; i < 32; ++i) {
    const int s  = i * NTHR + tid;
    const int dw = s & 3, n = (s >> 2) & 31, kgs = (s >> 7) & 1;
    const int js = (s >> 8) & 7, kos = s >> 11;
    const int grow = (n >> 3) * H_ + ug * UPB + (n & 7);
    const int k = kos * 128 + js * 16 + kgs * 8 + dw * 2;
    const unsigned byte = (unsigned)(kos * 8192 + js * 1024 + kgs * 512 + n * 16 + dw * 4);
    float2 v = *(const float2*)(Wx + (size_t)grow * D_ + k);
    *(unsigned*)(smem + byte) = f2bf(v.x) | (f2bf(v.y) << 16);
    v = *(const float2*)(Wh + (size_t)grow * H_ + k);
    *(unsigned*)(smem + WH_OFF + byte) = f2bf(v.x) | (f2bf(v.y) << 16);
  }
  if (tid < NROW) {
    const int grow = (tid >> 3) * H_ + ug * UPB + (tid & 7);
    bias_lds[tid] = bxp[grow] + bhp[grow];
  }

  const int lane = tid & 63;
  const int wid  = tid >> 6;   // 0..7 = K-eighth of 1024 (128 k)
  const int ko   = wid;
  const int l31  = lane & 31;  // A: batch row in half / B: gate row
  const int kg   = lane >> 5;  // 0..1
  const int b0   = bg * 32;

  const unsigned wxbase = (unsigned)(ko * 8192 + kg * 512 + l31 * 16);
#define LWX(J) (*(const short8*)(smem + wxbase + (unsigned)((J) * 1024)))
#define LWH(J) (*(const short8*)(smem + WH_OFF + wxbase + (unsigned)((J) * 1024)))
  // h frag j: kblk = ko*16 + j*2 + kg ; ull idx = (kblk*64 + b0+l31)*2
  const size_t hull0 = ((size_t)(ko * 16 + kg) * 64 + (b0 + l31)) * 2;
  // xp frag j (step nxt): shorts base + j*1024
  const size_t xsh0 = ((size_t)(ko * 16 + kg) * 64 + (b0 + l31)) * 8;

  const int act = (tid < 256);
  const int cb2 = (tid >> 3) & 31;
  const int cu  = tid & 7;
  const int b   = b0 + cb2;
  const int hu  = ug * UPB + cu;
  float ccell = 0.0f, hv = 0.0f;

  __syncthreads();  // weights staged

  // ---- preamble: accX = x(0)@Wx^T ; m(0) -> m_lds slot 0 ----
  f32x16 accX = {0,0,0,0,0,0,0,0,0,0,0,0,0,0,0,0};
  if (XB) {
    const unsigned short* xb = xp + xsh0;  // t=0
#pragma unroll
    for (int j = 0; j < 8; ++j)
      accX = __builtin_amdgcn_mfma_f32_32x32x16_bf16(
          *(const short8*)(xb + j * 1024), LWX(j), accX, 0, 0, 0);
  } else {
    const float* xsrc = xf + (size_t)(b0 + l31) * T_ * D_ + ko * 128 + kg * 8;
#pragma unroll
    for (int j = 0; j < 8; ++j) {
      float4 a0 = *(const float4*)(xsrc + j * 16);
      float4 a1 = *(const float4*)(xsrc + j * 16 + 4);
      short8 r;
      r[0] = (short)f2bf(a0.x); r[1] = (short)f2bf(a0.y);
      r[2] = (short)f2bf(a0.z); r[3] = (short)f2bf(a0.w);
      r[4] = (short)f2bf(a1.x); r[5] = (short)f2bf(a1.y);
      r[6] = (short)f2bf(a1.z); r[7] = (short)f2bf(a1.w);
      accX = __builtin_amdgcn_mfma_f32_32x32x16_bf16(r, LWX(j), accX, 0, 0, 0);
    }
  }
  if (tid < B_) m_lds[tid] = mT[tid];
  __syncthreads();  // m_lds(0) visible

  for (int t = 0; t < T_; ++t) {
    const int nxt = (t + 1 < T_) ? (t + 1) : t;
    const unsigned tgt = (unsigned)(t + 1);

    // ---- critical path: 8 h-frags (agent atomic 8B loads) -> 16 MFMAs ----
    const unsigned long long* hp =
        (const unsigned long long*)(hbuf + (size_t)(t & 1) * HSLOT) + hull0;
    short8 hf[8];
#pragma unroll
    for (int j = 0; j < 8; ++j) {
      unsigned long long lo = __hip_atomic_load(hp + (size_t)j * 256,
                                                __ATOMIC_RELAXED, __HIP_MEMORY_SCOPE_AGENT);
      unsigned long long hi = __hip_atomic_load(hp + (size_t)j * 256 + 1,
                                                __ATOMIC_RELAXED, __HIP_MEMORY_SCOPE_AGENT);
      ((unsigned long long*)&hf[j])[0] = lo;
      ((unsigned long long*)&hf[j])[1] = hi;
    }
    f32x16 accA = {0,0,0,0,0,0,0,0,0,0,0,0,0,0,0,0};  // h@Wx^T
    f32x16 accC = {0,0,0,0,0,0,0,0,0,0,0,0,0,0,0,0};  // h@Wh^T
#pragma unroll
    for (int j = 0; j < 8; ++j) {
      accA = __builtin_amdgcn_mfma_f32_32x32x16_bf16(hf[j], LWX(j), accA, 0, 0, 0);
      accC = __builtin_amdgcn_mfma_f32_32x32x16_bf16(hf[j], LWH(j), accC, 0, 0, 0);
    }

    // ---- epilogue: g = m*accA + (1-m)*accX + accC (+bias); 4-slab reduce ----
    // C layout (32x32): col = lane&31 (gate row), row = (e&3)+8*(e>>2)+4*kg
    // (batch WITHIN half -> mask index must add b0)
    const float* ml = m_lds + (t & 1) * B_;
    const int s = wid & 3;
    if (wid < 4) {
#pragma unroll
      for (int e = 0; e < 16; ++e) {
        const int br = (e & 3) + 8 * (e >> 2) + 4 * kg;
        const float mv = ml[b0 + br];
        float g = mv * accA[e] + (1.0f - mv) * accX[e] + accC[e];
        if (wid == 0) g += bias_lds[l31];
        gbuf[(s * 32 + br) * 33 + l31] = g;
      }
    }
    __syncthreads();  // (B)
    if (wid >= 4) {
#pragma unroll
      for (int e = 0; e < 16; ++e) {
        const int br = (e & 3) + 8 * (e >> 2) + 4 * kg;
        const float mv = ml[b0 + br];
        gbuf[(s * 32 + br) * 33 + l31] += mv * accA[e] + (1.0f - mv) * accX[e] + accC[e];
      }
    }
    __syncthreads();  // (C)

    // ---- cell: one (b,u) per thread (tid<256); single h store ----
    if (act) {
      float gi = 0.0f, gf = 0.0f, gg = 0.0f, go = 0.0f;
#pragma unroll
      for (int sl = 0; sl < 4; ++sl) {
        const float* row = gbuf + (sl * 32 + cb2) * 33;
        gi += row[cu];      gf += row[8 + cu];
        gg += row[16 + cu]; go += row[24 + cu];
      }
      const float iv = sigf(gi), fv = sigf(gf), gv = tanhf_(gg), ov = sigf(go);
      ccell = ccell * fv + iv * gv;
      hv = ov * tanhf_(ccell);
      // kblk = hu>>3 = ug -> block writes 512B contiguous at ug*1024B
      __hip_atomic_store(hbuf + (size_t)((t + 1) & 1) * HSLOT +
                             ((hu >> 3) * 64 + b) * 8 + (hu & 7),
                         (unsigned short)f2bf(hv),
                         __ATOMIC_RELAXED, __HIP_MEMORY_SCOPE_AGENT);
    }

    __syncthreads();  // (D) drains h stores (vmcnt(0) before s_barrier)

    if (bid == 0) {  // master: poll all 256 flags, publish gen (R11 verbatim)
      if (wid == 0) {
        for (;;) {
          unsigned v0 = (lane == 0) ? tgt
              : __hip_atomic_load(flags + lane, __ATOMIC_RELAXED, __HIP_MEMORY_SCOPE_AGENT);
          unsigned v1 = __hip_atomic_load(flags + 64 + lane,
                                          __ATOMIC_RELAXED, __HIP_MEMORY_SCOPE_AGENT);
          unsigned v2 = __hip_atomic_load(flags + 128 + lane,
                                          __ATOMIC_RELAXED, __HIP_MEMORY_SCOPE_AGENT);
          unsigned v3 = __hip_atomic_load(flags + 192 + lane,
                                          __ATOMIC_RELAXED, __HIP_MEMORY_SCOPE_AGENT);
          if (__all((v0 >= tgt) && (v1 >= tgt) && (v2 >= tgt) && (v3 >= tgt))) break;
          __builtin_amdgcn_s_sleep(1);
        }
        if (lane == 0)
          __hip_atomic_store(gen, tgt, __ATOMIC_RELAXED, __HIP_MEMORY_SCOPE_AGENT);
      }
    } else {
      if (tid == 0)
        __hip_atomic_store(flags + bid, tgt,
                           __ATOMIC_RELAXED, __HIP_MEMORY_SCOPE_AGENT);
    }

    // ---- SLACK (after own flag, before gen wait): out, x(t+1)@Wx, m(t+1) ----
    if (act) out[((size_t)b * T_ + t) * H_ + hu] = hv;
    f32x16 accXn = {0,0,0,0,0,0,0,0,0,0,0,0,0,0,0,0};
    if (XB) {
      const unsigned short* xb = xp + (size_t)nxt * (128 * 64 * 8) + xsh0;
#pragma unroll
      for (int j = 0; j < 8; ++j)
        accXn = __builtin_amdgcn_mfma_f32_32x32x16_bf16(
            *(const short8*)(xb + j * 1024), LWX(j), accXn, 0, 0, 0);
    } else {
      const float* xsrc = xf + ((size_t)(b0 + l31) * T_ + nxt) * D_ + ko * 128 + kg * 8;
#pragma unroll
      for (int j = 0; j < 8; ++j) {
        float4 a0 = *(const float4*)(xsrc + j * 16);
        float4 a1 = *(const float4*)(xsrc + j * 16 + 4);
        short8 r;
        r[0] = (short)f2bf(a0.x); r[1] = (short)f2bf(a0.y);
        r[2] = (short)f2bf(a0.z); r[3] = (short)f2bf(a0.w);
        r[4] = (short)f2bf(a1.x); r[5] = (short)f2bf(a1.y);
        r[6] = (short)f2bf(a1.z); r[7] = (short)f2bf(a1.w);
        accXn = __builtin_amdgcn_mfma_f32_32x32x16_bf16(r, LWX(j), accXn, 0, 0, 0);
      }
    }
    if (tid < B_) m_lds[((t + 1) & 1) * B_ + tid] = mT[nxt * B_ + tid];

    if (bid != 0 && wid == 0) {
      while (__hip_atomic_load(gen, __ATOMIC_RELAXED, __HIP_MEMORY_SCOPE_AGENT) < tgt)
        __builtin_amdgcn_s_sleep(1);
    }
    __syncthreads();  // (E)
    __builtin_amdgcn_sched_barrier(0);  // nothing hoists above the wait

    accX = accXn;
  }

  // finals: hn, cn
  if (act) {
    out[(size_t)B_ * T_ * H_ + (size_t)b * H_ + hu] = hv;
    out[(size_t)B_ * T_ * H_ + (size_t)B_ * H_ + (size_t)b * H_ + hu] = ccell;
  }
}

extern "C" void kernel_launch(void* const* d_in, const int* in_sizes, int n_in,
                              void* d_out, int out_size, void* d_ws, size_t ws_size,
                              hipStream_t stream) {
  const float* x  = (const float*)d_in[0];
  const float* tm = (const float*)d_in[1];
  const float* Wx = (const float*)d_in[2];
  const float* bx = (const float*)d_in[3];
  const float* Wh = (const float*)d_in[4];
  const float* bh = (const float*)d_in[5];
  float* out = (float*)d_out;
  char* ws = (char*)d_ws;

  unsigned* flags      = (unsigned*)ws;
  unsigned* gen        = (unsigned*)(ws + 2048);
  float* mT            = (float*)(ws + WS_MT);
  unsigned short* hbuf = (unsigned short*)(ws + WS_HBUF);
  unsigned short* xp   = (unsigned short*)(ws + WS_XP);

  const size_t need_xp = (size_t)WS_XP + 2ull * B_ * T_ * D_;
  const bool use_xp = ws_size >= need_xp;

  // zero flags + gen + mT(region) + both h slots (h(0)=0)
  hipMemsetAsync(ws, 0, WS_HBUF + 2 * HSLOT * 2, stream);
  prep_m<<<dim3((B_ * T_ + 255) / 256), dim3(256), 0, stream>>>(tm, mT);
  if (use_xp) {
    const int n = B_ * T_ * D_ / 8;
    prep_x<<<dim3((n + 255) / 256), dim3(256), 0, stream>>>(x, xp);
    lstm_persist<1><<<dim3(NBLK), dim3(NTHR), SMEM_BYTES, stream>>>(
        x, xp, mT, Wx, bx, Wh, bh, out, hbuf, flags, gen);
  } else {
    lstm_persist<0><<<dim3(NBLK), dim3(NTHR), SMEM_BYTES, stream>>>(
        x, xp, mT, Wx, bx, Wh, bh, out, hbuf, flags, gen);
  }
}

// Round 15
// 2715.112 us; speedup vs baseline: 1.0413x; 1.0413x over previous
//
#include <hip/hip_runtime.h>
#include <stdint.h>

// Teacher-forced LSTM, B=64 T=512 D=H=1024.
// gates(t) = m(t)*(h@Wx^T) + (1-m(t))*(x(t)@Wx^T) + h@Wh^T + bias, h=h(t-1)
// x(t+1)@Wx^T computed in step t's slack (all compute waves, after flag).
// Persistent: 256 blocks x 576 thr (9 waves) = 128 unit-groups x 2 batch-halves.
// Waves 0-7: GEMM/epilogue/cell/slack. WAVE 8 = protocol wave: in blocks 0/1
// it polls its domain's 128 flags and publishes gen[domain]; in all blocks it
// waits on gen[domain]; compute waves never poll (R14's master-slack
// serialization removed). Two sync domains (one per batch half) each keep the
// master->gen settle hop (R12 lesson). h-only panel hbuf[2][128 kblk][64 b][8]
// bf16; producers agent write-through stores; consumers agent atomic 8B loads.
// Weights bf16 128KB LDS-stationary, conflict-free. 32x32x16 MFMA.

#define B_ 64
#define T_ 512
#define D_ 1024
#define H_ 1024
#define NBLK 256
#define UPB 8
#define NROW 32
#define BTHR 576   /* 9 waves */

typedef __attribute__((ext_vector_type(8))) short short8;
typedef __attribute__((ext_vector_type(16))) float f32x16;

// LDS (bytes): Wx @0 64KB | Wh @65536 64KB | gbuf f32[4][32][33] @131072 |
// m_lds f32[2][64] @147968 | bias f32[32] @148480
#define WH_OFF 65536
#define GBUF_OFF 131072
#define MLDS_OFF 147968
#define BIAS_OFF 148480
#define SMEM_BYTES 148608

// ws (bytes): flags[2][128] u32 @0 | gen[2] u32 @2048 (128B apart) |
// mT f32[512][64] @4096 | hbuf @135168: [2][128 kblk][64 b][8] bf16 |
// xp @397312: [512 t][128 dblk][64 b][8] bf16
#define WS_MT 4096
#define WS_HBUF 135168
#define WS_XP 397312
#define HSLOT 65536 /* shorts per h slot (131072 B) */

__device__ __forceinline__ unsigned f2bf(float f) {  // fp32 -> bf16 RNE
  unsigned u = __float_as_uint(f);
  return (u + 0x7FFFu + ((u >> 16) & 1u)) >> 16;
}
__device__ __forceinline__ float sigf(float x) { return 1.0f / (1.0f + __expf(-x)); }
__device__ __forceinline__ float tanhf_(float x) { return 1.0f - 2.0f / (__expf(2.0f * x) + 1.0f); }

__global__ void prep_m(const float* __restrict__ tm, float* __restrict__ mT) {
  int i = blockIdx.x * blockDim.x + threadIdx.x;  // over B*T
  if (i >= B_ * T_) return;
  int b = i >> 9, t = i & (T_ - 1);
  mT[t * B_ + b] = tm[i];
}

// xp[((t*128 + dblk)*64 + b)*8 + s] = bf16(x[b][t][dblk*8+s]); coalesced reads.
__global__ void prep_x(const float* __restrict__ x, unsigned short* __restrict__ xp) {
  int i = blockIdx.x * blockDim.x + threadIdx.x;  // over B*T*D/8
  if (i >= B_ * T_ * D_ / 8) return;
  const int dblk = i & 127, t = (i >> 7) & (T_ - 1), b = i >> 16;
  const float* src = x + ((size_t)b * T_ + t) * D_ + dblk * 8;
  float4 a0 = *(const float4*)src;
  float4 a1 = *(const float4*)(src + 4);
  short8 r;
  r[0] = (short)f2bf(a0.x); r[1] = (short)f2bf(a0.y);
  r[2] = (short)f2bf(a0.z); r[3] = (short)f2bf(a0.w);
  r[4] = (short)f2bf(a1.x); r[5] = (short)f2bf(a1.y);
  r[6] = (short)f2bf(a1.z); r[7] = (short)f2bf(a1.w);
  *(short8*)(xp + ((size_t)(t * 128 + dblk) * 64 + b) * 8) = r;
}

template<int XB>
__global__ __launch_bounds__(BTHR, 1)
void lstm_persist(const float* __restrict__ xf,
                  const unsigned short* __restrict__ xp,
                  const float* __restrict__ mT,
                  const float* __restrict__ Wx, const float* __restrict__ bxp,
                  const float* __restrict__ Wh, const float* __restrict__ bhp,
                  float* __restrict__ out,
                  unsigned short* __restrict__ hbuf,
                  unsigned* __restrict__ flags,
                  unsigned* __restrict__ gen)
{
  extern __shared__ char smem[];
  float* gbuf     = (float*)(smem + GBUF_OFF);  // [4][32][33]
  float* m_lds    = (float*)(smem + MLDS_OFF);  // [2][64]
  float* bias_lds = (float*)(smem + BIAS_OFF);

  const int tid = threadIdx.x;
  const int bid = blockIdx.x;
  const int ug  = bid >> 1;   // unit group 0..127
  const int bg  = bid & 1;    // batch half / sync domain

  // ---- stage Wx,Wh -> LDS (first 512 threads), conflict-free layout ----
  if (tid < 512) {
    for (int i = 0; i < 32; ++i) {
      const int s  = i * 512 + tid;
      const int dw = s & 3, n = (s >> 2) & 31, kgs = (s >> 7) & 1;
      const int js = (s >> 8) & 7, kos = s >> 11;
      const int grow = (n >> 3) * H_ + ug * UPB + (n & 7);
      const int k = kos * 128 + js * 16 + kgs * 8 + dw * 2;
      const unsigned byte = (unsigned)(kos * 8192 + js * 1024 + kgs * 512 + n * 16 + dw * 4);
      float2 v = *(const float2*)(Wx + (size_t)grow * D_ + k);
      *(unsigned*)(smem + byte) = f2bf(v.x) | (f2bf(v.y) << 16);
      v = *(const float2*)(Wh + (size_t)grow * H_ + k);
      *(unsigned*)(smem + WH_OFF + byte) = f2bf(v.x) | (f2bf(v.y) << 16);
    }
  }
  if (tid < NROW) {
    const int grow = (tid >> 3) * H_ + ug * UPB + (tid & 7);
    bias_lds[tid] = bxp[grow] + bhp[grow];
  }

  const int lane = tid & 63;
  const int wid  = tid >> 6;   // 0..8; 8 = protocol wave
  const int ko   = wid & 7;    // K-eighth of 1024 (128 k) for compute waves
  const int l31  = lane & 31;
  const int kg   = lane >> 5;
  const int b0   = bg * 32;

  const unsigned wxbase = (unsigned)(ko * 8192 + kg * 512 + l31 * 16);
#define LWX(J) (*(const short8*)(smem + wxbase + (unsigned)((J) * 1024)))
#define LWH(J) (*(const short8*)(smem + WH_OFF + wxbase + (unsigned)((J) * 1024)))
  const size_t hull0 = ((size_t)(ko * 16 + kg) * 64 + (b0 + l31)) * 2;
  const size_t xsh0  = ((size_t)(ko * 16 + kg) * 64 + (b0 + l31)) * 8;

  const int act = (tid < 256);
  const int cb2 = (tid >> 3) & 31;
  const int cu  = tid & 7;
  const int b   = b0 + cb2;
  const int hu  = ug * UPB + cu;
  unsigned* dom_flags = flags + (bg << 7);
  unsigned* dom_gen   = gen + bg * 32;  // 128B apart
  float ccell = 0.0f, hv = 0.0f;

  __syncthreads();  // weights staged

  // ---- preamble: accX = x(0)@Wx^T ; m(0) ----
  f32x16 accX = {0,0,0,0,0,0,0,0,0,0,0,0,0,0,0,0};
  if (wid < 8) {
    if (XB) {
      const unsigned short* xb = xp + xsh0;  // t=0
#pragma unroll
      for (int j = 0; j < 8; ++j)
        accX = __builtin_amdgcn_mfma_f32_32x32x16_bf16(
            *(const short8*)(xb + j * 1024), LWX(j), accX, 0, 0, 0);
    } else {
      const float* xsrc = xf + (size_t)(b0 + l31) * T_ * D_ + ko * 128 + kg * 8;
#pragma unroll
      for (int j = 0; j < 8; ++j) {
        float4 a0 = *(const float4*)(xsrc + j * 16);
        float4 a1 = *(const float4*)(xsrc + j * 16 + 4);
        short8 r;
        r[0] = (short)f2bf(a0.x); r[1] = (short)f2bf(a0.y);
        r[2] = (short)f2bf(a0.z); r[3] = (short)f2bf(a0.w);
        r[4] = (short)f2bf(a1.x); r[5] = (short)f2bf(a1.y);
        r[6] = (short)f2bf(a1.z); r[7] = (short)f2bf(a1.w);
        accX = __builtin_amdgcn_mfma_f32_32x32x16_bf16(r, LWX(j), accX, 0, 0, 0);
      }
    }
  }
  if (tid < B_) m_lds[tid] = mT[tid];
  __syncthreads();  // m_lds(0) visible

  for (int t = 0; t < T_; ++t) {
    const int nxt = (t + 1 < T_) ? (t + 1) : t;
    const unsigned tgt = (unsigned)(t + 1);

    // ---- critical path (compute waves): 8 h-frags -> 16 MFMAs ----
    f32x16 accA = {0,0,0,0,0,0,0,0,0,0,0,0,0,0,0,0};
    f32x16 accC = {0,0,0,0,0,0,0,0,0,0,0,0,0,0,0,0};
    if (wid < 8) {
      const unsigned long long* hp =
          (const unsigned long long*)(hbuf + (size_t)(t & 1) * HSLOT) + hull0;
      short8 hf[8];
#pragma unroll
      for (int j = 0; j < 8; ++j) {
        unsigned long long lo = __hip_atomic_load(hp + (size_t)j * 256,
                                                  __ATOMIC_RELAXED, __HIP_MEMORY_SCOPE_AGENT);
        unsigned long long hi = __hip_atomic_load(hp + (size_t)j * 256 + 1,
                                                  __ATOMIC_RELAXED, __HIP_MEMORY_SCOPE_AGENT);
        ((unsigned long long*)&hf[j])[0] = lo;
        ((unsigned long long*)&hf[j])[1] = hi;
      }
#pragma unroll
      for (int j = 0; j < 8; ++j) {
        accA = __builtin_amdgcn_mfma_f32_32x32x16_bf16(hf[j], LWX(j), accA, 0, 0, 0);
        accC = __builtin_amdgcn_mfma_f32_32x32x16_bf16(hf[j], LWH(j), accC, 0, 0, 0);
      }
    }

    // ---- epilogue: g = m*accA + (1-m)*accX + accC (+bias); 4-slab reduce ----
    const float* ml = m_lds + (t & 1) * B_;
    const int s = wid & 3;
    if (wid < 4) {
#pragma unroll
      for (int e = 0; e < 16; ++e) {
        const int br = (e & 3) + 8 * (e >> 2) + 4 * kg;
        const float mv = ml[b0 + br];
        float g = mv * accA[e] + (1.0f - mv) * accX[e] + accC[e];
        if (wid == 0) g += bias_lds[l31];
        gbuf[(s * 32 + br) * 33 + l31] = g;
      }
    }
    __syncthreads();  // (B)
    if (wid >= 4 && wid < 8) {
#pragma unroll
      for (int e = 0; e < 16; ++e) {
        const int br = (e & 3) + 8 * (e >> 2) + 4 * kg;
        const float mv = ml[b0 + br];
        gbuf[(s * 32 + br) * 33 + l31] += mv * accA[e] + (1.0f - mv) * accX[e] + accC[e];
      }
    }
    __syncthreads();  // (C)

    // ---- cell: one (b,u) per thread (tid<256) ----
    if (act) {
      float gi = 0.0f, gf = 0.0f, gg = 0.0f, go = 0.0f;
#pragma unroll
      for (int sl = 0; sl < 4; ++sl) {
        const float* row = gbuf + (sl * 32 + cb2) * 33;
        gi += row[cu];      gf += row[8 + cu];
        gg += row[16 + cu]; go += row[24 + cu];
      }
      const float iv = sigf(gi), fv = sigf(gf), gv = tanhf_(gg), ov = sigf(go);
      ccell = ccell * fv + iv * gv;
      hv = ov * tanhf_(ccell);
      __hip_atomic_store(hbuf + (size_t)((t + 1) & 1) * HSLOT +
                             ((hu >> 3) * 64 + b) * 8 + (hu & 7),
                         (unsigned short)f2bf(hv),
                         __ATOMIC_RELAXED, __HIP_MEMORY_SCOPE_AGENT);
    }

    __syncthreads();  // (D) drains h stores (vmcnt(0) before s_barrier)
    if (tid == 0)
      __hip_atomic_store(dom_flags + ug, tgt,
                         __ATOMIC_RELAXED, __HIP_MEMORY_SCOPE_AGENT);

    // ---- protocol wave: domain master poll + gen, then gen wait ----
    if (wid == 8) {
      if (bid == bg) {  // blocks 0 and 1 are the two domain masters
        for (;;) {
          unsigned v0 = __hip_atomic_load(dom_flags + lane,
                                          __ATOMIC_RELAXED, __HIP_MEMORY_SCOPE_AGENT);
          unsigned v1 = __hip_atomic_load(dom_flags + 64 + lane,
                                          __ATOMIC_RELAXED, __HIP_MEMORY_SCOPE_AGENT);
          if (__all((v0 >= tgt) && (v1 >= tgt))) break;
          __builtin_amdgcn_s_sleep(1);
        }
        if (lane == 0)
          __hip_atomic_store(dom_gen, tgt, __ATOMIC_RELAXED, __HIP_MEMORY_SCOPE_AGENT);
      }
      while (__hip_atomic_load(dom_gen, __ATOMIC_RELAXED, __HIP_MEMORY_SCOPE_AGENT) < tgt)
        __builtin_amdgcn_s_sleep(1);
    }

    // ---- slack (compute waves, overlaps protocol): out, x(t+1)@Wx, m(t+1) ----
    if (act) out[((size_t)b * T_ + t) * H_ + hu] = hv;
    f32x16 accXn = {0,0,0,0,0,0,0,0,0,0,0,0,0,0,0,0};
    if (wid < 8) {
      if (XB) {
        const unsigned short* xb = xp + (size_t)nxt * (128 * 64 * 8) + xsh0;
#pragma unroll
        for (int j = 0; j < 8; ++j)
          accXn = __builtin_amdgcn_mfma_f32_32x32x16_bf16(
              *(const short8*)(xb + j * 1024), LWX(j), accXn, 0, 0, 0);
      } else {
        const float* xsrc = xf + ((size_t)(b0 + l31) * T_ + nxt) * D_ + ko * 128 + kg * 8;
#pragma unroll
        for (int j = 0; j < 8; ++j) {
          float4 a0 = *(const float4*)(xsrc + j * 16);
          float4 a1 = *(const float4*)(xsrc + j * 16 + 4);
          short8 r;
          r[0] = (short)f2bf(a0.x); r[1] = (short)f2bf(a0.y);
          r[2] = (short)f2bf(a0.z); r[3] = (short)f2bf(a0.w);
          r[4] = (short)f2bf(a1.x); r[5] = (short)f2bf(a1.y);
          r[6] = (short)f2bf(a1.z); r[7] = (short)f2bf(a1.w);
          accXn = __builtin_amdgcn_mfma_f32_32x32x16_bf16(r, LWX(j), accXn, 0, 0, 0);
        }
      }
    }
    if (tid < B_) m_lds[((t + 1) & 1) * B_ + tid] = mT[nxt * B_ + tid];

    __syncthreads();  // (E) gates on wave 8's gen observation
    accX = accXn;
  }

  // finals: hn, cn
  if (act) {
    out[(size_t)B_ * T_ * H_ + (size_t)b * H_ + hu] = hv;
    out[(size_t)B_ * T_ * H_ + (size_t)B_ * H_ + (size_t)b * H_ + hu] = ccell;
  }
}

extern "C" void kernel_launch(void* const* d_in, const int* in_sizes, int n_in,
                              void* d_out, int out_size, void* d_ws, size_t ws_size,
                              hipStream_t stream) {
  const float* x  = (const float*)d_in[0];
  const float* tm = (const float*)d_in[1];
  const float* Wx = (const float*)d_in[2];
  const float* bx = (const float*)d_in[3];
  const float* Wh = (const float*)d_in[4];
  const float* bh = (const float*)d_in[5];
  float* out = (float*)d_out;
  char* ws = (char*)d_ws;

  unsigned* flags      = (unsigned*)ws;
  unsigned* gen        = (unsigned*)(ws + 2048);
  float* mT            = (float*)(ws + WS_MT);
  unsigned short* hbuf = (unsigned short*)(ws + WS_HBUF);
  unsigned short* xp   = (unsigned short*)(ws + WS_XP);

  const size_t need_xp = (size_t)WS_XP + 2ull * B_ * T_ * D_;
  const bool use_xp = ws_size >= need_xp;

  // zero flags + gen + mT(region) + both h slots (h(0)=0)
  hipMemsetAsync(ws, 0, WS_HBUF + 2 * HSLOT * 2, stream);
  prep_m<<<dim3((B_ * T_ + 255) / 256), dim3(256), 0, stream>>>(tm, mT);
  if (use_xp) {
    const int n = B_ * T_ * D_ / 8;
    prep_x<<<dim3((n + 255) / 256), dim3(256), 0, stream>>>(x, xp);
    lstm_persist<1><<<dim3(NBLK), dim3(BTHR), SMEM_BYTES, stream>>>(
        x, xp, mT, Wx, bx, Wh, bh, out, hbuf, flags, gen);
  } else {
    lstm_persist<0><<<dim3(NBLK), dim3(BTHR), SMEM_BYTES, stream>>>(
        x, xp, mT, Wx, bx, Wh, bh, out, hbuf, flags, gen);
  }
}